// Round 10
// baseline (44.705 us; speedup 1.0000x reference)
//
#include <hip/hip_runtime.h>

#define NT  128  // 2 waves/block; waves fully independent (zero __syncthreads)
#define WSZ 64
#define NJ  22

// parent table (compile-time indexed only)
constexpr int PARENT[NJ] = {0,0,0,0,1,2,3,4,5,6,7,8,9,9,9,12,13,14,16,17,18,19};

struct X9 { float r[9]; float t[3]; };

__device__ __forceinline__ void rodrigues(float ax, float ay, float az, float* R) {
    float sq   = ax*ax + ay*ay + az*az + 1e-12f;
    float rinv = rsqrtf(sq);
    float ang  = sq * rinv;          // sqrt(sq)
    float s, c;
    __sincosf(ang, &s, &c);
    float x = ax*rinv, y = ay*rinv, z = az*rinv;
    float t = 1.0f - c;
    R[0] = t*x*x + c;   R[1] = t*x*y - s*z; R[2] = t*x*z + s*y;
    R[3] = t*x*y + s*z; R[4] = t*y*y + c;   R[5] = t*y*z - s*x;
    R[6] = t*x*z - s*y; R[7] = t*y*z + s*x; R[8] = t*z*z + c;
}

// One FK step. Pose read from LDS (per-lane, stride-63); local position from
// REGISTERS (sk, compile-time index); output written back into the just-consumed
// pose slot (WAR-safe: per-wave DS pipe is in-order). Zero table traffic.
template<int J>
__device__ __forceinline__ X9 step(const X9& gp, float* pp, const float* sk) {
    float R[9];
    rodrigues(pp[(J-1)*3 + 0], pp[(J-1)*3 + 1], pp[(J-1)*3 + 2], R);
    const float l0 = sk[J*3+0], l1 = sk[J*3+1], l2 = sk[J*3+2];
    X9 g;
    #pragma unroll
    for (int r = 0; r < 3; ++r) {
        #pragma unroll
        for (int c = 0; c < 3; ++c)
            g.r[r*3+c] = fmaf(gp.r[r*3+0], R[c],
                         fmaf(gp.r[r*3+1], R[3+c],
                              gp.r[r*3+2] * R[6+c]));
        g.t[r] = fmaf(gp.r[r*3+0], l0,
                 fmaf(gp.r[r*3+1], l1,
                 fmaf(gp.r[r*3+2], l2, gp.t[r])));
    }
    pp[(J-1)*3+0] = g.t[0]; pp[(J-1)*3+1] = g.t[1]; pp[(J-1)*3+2] = g.t[2];
    return g;
}

__global__ __launch_bounds__(NT) void fk_joints_kernel(
    const float* __restrict__ body_pose,     // (S,63)
    const float* __restrict__ betas,         // (S,10)
    const float* __restrict__ global_orient, // (S,3)
    const float* __restrict__ transl,        // (S,3)
    const float* __restrict__ J_template,    // (22,3)   -> s_load (uniform idx)
    const float* __restrict__ J_shapedirs,   // (22,3,10)-> s_load (uniform idx)
    float* __restrict__ out)                 // (S,22,3)
{
    // Wave-private pose regions (64 samples x 63 floats). FK outputs for joint J
    // overwrite the pose slot (J-1) right after it is consumed. Root -> s_root.
    __shared__ float s_buf[NT*63];           // 32256 B
    __shared__ float s_root[NT*3];           // 1536 B   (total 33792 B -> 4 blk/CU)

    const int  tid  = threadIdx.x;
    const int  lane = tid & (WSZ-1);
    const int  wid  = tid >> 6;
    const long long sw = (long long)blockIdx.x * NT + (long long)wid * WSZ;
    const long long s  = sw + lane;

    float* myb = s_buf + wid * (WSZ*63);

    // ---- 1) stage OWN wave's pose chunk (coalesced float4) ----
    {
        const float4* src = reinterpret_cast<const float4*>(body_pose + sw*63);
        float4* dst = reinterpret_cast<float4*>(myb);
        for (int i = lane; i < WSZ*63/4; i += WSZ) dst[i] = src[i];   // 1008 f4
    }

    // ---- 2) per-lane small inputs (fill under staging) ----
    const float gox = global_orient[s*3 + 0];
    const float goy = global_orient[s*3 + 1];
    const float goz = global_orient[s*3 + 2];
    const float trx = transl[s*3 + 0];
    const float try_ = transl[s*3 + 1];
    const float trz = transl[s*3 + 2];
    float bt[10];
    {
        const float2* b2 = reinterpret_cast<const float2*>(betas + s*10);
        #pragma unroll
        for (int k = 0; k < 5; ++k) {
            float2 v = b2[k];
            bt[2*k+0] = v.x; bt[2*k+1] = v.y;
        }
    }

    // ---- 3) per-sample skeleton einsum IN REGISTERS; table via s_load/SGPR ----
    float sk[NJ*3];
    #pragma unroll
    for (int j = 0; j < NJ; ++j) {
        #pragma unroll
        for (int c = 0; c < 3; ++c) {
            float v = J_template[j*3 + c];                 // uniform -> SGPR
            #pragma unroll
            for (int k = 0; k < 10; ++k)
                v = fmaf(bt[k], J_shapedirs[(j*3 + c)*10 + k], v);  // v_fmac v,s,v
            sk[j*3 + c] = v;
        }
    }
    // parent diffs in-place (children have higher index; descend)
    #pragma unroll
    for (int j = NJ-1; j >= 1; --j) {
        #pragma unroll
        for (int c = 0; c < 3; ++c) sk[j*3 + c] -= sk[PARENT[j]*3 + c];
    }

    // ---- 4) root transform ----
    X9 g0;
    rodrigues(gox, goy, goz, g0.r);
    g0.t[0] = sk[0] + trx;
    g0.t[1] = sk[1] + try_;
    g0.t[2] = sk[2] + trz;
    s_root[tid*3+0] = g0.t[0]; s_root[tid*3+1] = g0.t[1]; s_root[tid*3+2] = g0.t[2];

    __builtin_amdgcn_wave_barrier();   // fence: staging writes before step pose reads

    // ---- 5) FK chains: pose from LDS per step, locals from regs, out in-place ----
    float* pp = myb + lane*63;

    X9 g;
    // chain A: 0 -> 1 -> 4 -> 7 -> 10
    g = step<1 >(g0, pp, sk);
    g = step<4 >(g,  pp, sk);
    g = step<7 >(g,  pp, sk);
    g = step<10>(g,  pp, sk);
    // chain B: 0 -> 2 -> 5 -> 8 -> 11
    g = step<2 >(g0, pp, sk);
    g = step<5 >(g,  pp, sk);
    g = step<8 >(g,  pp, sk);
    g = step<11>(g,  pp, sk);
    // chain C: 0 -> 3 -> 6 -> 9
    g = step<3 >(g0, pp, sk);
    g = step<6 >(g,  pp, sk);
    X9 g9 = step<9>(g, pp, sk);
    // chain D: 9 -> 12 -> 15
    g = step<12>(g9, pp, sk);
    g = step<15>(g,  pp, sk);
    // chain E: 9 -> 13 -> 16 -> 18 -> 20
    g = step<13>(g9, pp, sk);
    g = step<16>(g,  pp, sk);
    g = step<18>(g,  pp, sk);
    g = step<20>(g,  pp, sk);
    // chain F: 9 -> 14 -> 17 -> 19 -> 21
    g = step<14>(g9, pp, sk);
    g = step<17>(g,  pp, sk);
    g = step<19>(g,  pp, sk);
    g = step<21>(g,  pp, sk);

    __builtin_amdgcn_wave_barrier();   // fence: FK writes before gather reads

    // ---- 6) coalesced float4 gather of OWN wave's outputs ----
    // sample sm: root in s_root, joints 1..21 at myb[sm*63 + (j-1)*3 + c]
    {
        const float* s_rootw = s_root + wid * (WSZ*3);
        float4* dst = reinterpret_cast<float4*>(out + sw * (NJ*3));
        for (int i = lane; i < WSZ*66/4; i += WSZ) {     // 1056 f4
            const int f0 = i*4;
            float v[4];
            #pragma unroll
            for (int q = 0; q < 4; ++q) {
                int f = f0 + q;
                int sm = f / 66;
                int r = f - sm*66;
                v[q] = (r < 3) ? s_rootw[sm*3 + r] : myb[sm*63 + (r - 3)];
            }
            dst[i] = make_float4(v[0], v[1], v[2], v[3]);
        }
    }
}

extern "C" void kernel_launch(void* const* d_in, const int* in_sizes, int n_in,
                              void* d_out, int out_size, void* d_ws, size_t ws_size,
                              hipStream_t stream) {
    const float* body_pose     = (const float*)d_in[0];
    const float* betas         = (const float*)d_in[1];
    const float* global_orient = (const float*)d_in[2];
    const float* transl        = (const float*)d_in[3];
    const float* J_template    = (const float*)d_in[4];
    const float* J_shapedirs   = (const float*)d_in[5];
    float* out = (float*)d_out;

    const int S = in_sizes[0] / 63;        // B*L = 131072 (divisible by NT)
    const int blocks = S / NT;

    hipLaunchKernelGGL(fk_joints_kernel, dim3(blocks), dim3(NT), 0, stream,
                       body_pose, betas, global_orient, transl,
                       J_template, J_shapedirs, out);
}

// Round 11
// 34.117 us; speedup vs baseline: 1.3104x; 1.3104x over previous
//
#include <hip/hip_runtime.h>

#define NT  128  // 2 waves/block; waves fully independent (zero __syncthreads)
#define WSZ 64
#define NJ  22

// FK schedule: code = j | (src<<8); src: 0=prev g, 1=g0, 2=g9
__constant__ int c_code[21] = {
    1|(1<<8), 4, 7, 10,            // chain A (from g0)
    2|(1<<8), 5, 8, 11,            // chain B (from g0)
    3|(1<<8), 6, 9,                // chain C (from g0); g9 captured at j==9
    12|(2<<8), 15,                 // chain D (from g9)
    13|(2<<8), 16, 18, 20,         // chain E (from g9)
    14|(2<<8), 17, 19, 21          // chain F (from g9)
};
__constant__ int c_par[NJ] = {0,0,0,0,1,2,3,4,5,6,7,8,9,9,9,12,13,14,16,17,18,19};

__device__ __forceinline__ void rodrigues(float ax, float ay, float az, float* R) {
    float sq   = ax*ax + ay*ay + az*az + 1e-12f;
    float rinv = rsqrtf(sq);
    float ang  = sq * rinv;          // sqrt(sq)
    float s, c;
    __sincosf(ang, &s, &c);
    float x = ax*rinv, y = ay*rinv, z = az*rinv;
    float t = 1.0f - c;
    R[0] = t*x*x + c;   R[1] = t*x*y - s*z; R[2] = t*x*z + s*y;
    R[3] = t*x*y + s*z; R[4] = t*y*y + c;   R[5] = t*y*z - s*x;
    R[6] = t*x*z - s*y; R[7] = t*y*z + s*x; R[8] = t*z*z + c;
}

// Row layout (12 floats): [d0..d9, LT, 0].  local = LT + sum_k bt[k]*d[k]
__device__ __forceinline__ void local_pos_rt(int j, const float* bt,
                                             const float4* LD4, float* lt) {
    #pragma unroll
    for (int c = 0; c < 3; ++c) {
        const float4 a0 = LD4[(j*3 + c)*3 + 0];
        const float4 a1 = LD4[(j*3 + c)*3 + 1];
        const float4 a2 = LD4[(j*3 + c)*3 + 2];
        float v = a2.z;                                  // LT in pad slot
        v = fmaf(bt[0], a0.x, v); v = fmaf(bt[1], a0.y, v);
        v = fmaf(bt[2], a0.z, v); v = fmaf(bt[3], a0.w, v);
        v = fmaf(bt[4], a1.x, v); v = fmaf(bt[5], a1.y, v);
        v = fmaf(bt[6], a1.z, v); v = fmaf(bt[7], a1.w, v);
        v = fmaf(bt[8], a2.x, v); v = fmaf(bt[9], a2.y, v);
        lt[c] = v;
    }
}

__global__ __launch_bounds__(NT) void fk_joints_kernel(
    const float* __restrict__ body_pose,     // (S,63)
    const float* __restrict__ betas,         // (S,10)
    const float* __restrict__ global_orient, // (S,3)
    const float* __restrict__ transl,        // (S,3)
    const float* __restrict__ J_template,    // (22,3)
    const float* __restrict__ J_shapedirs,   // (22,3,10)
    float* __restrict__ out)                 // (S,22,3)
{
    // Wave-private pose regions (64 x 63 floats), in-place output overlay (each
    // slot read exactly once, then overwritten). Root positions -> s_root.
    // Small rolled code -> entire kernel text stays I$-resident.
    __shared__ float  s_buf[NT*63];          // 32256 B
    __shared__ float  s_root[NT*3];          // 1536 B
    __shared__ float4 s_LD4[NJ*3*3];         // 3168 B  (total ~36.9 KB -> 4 blk/CU)

    const int  tid  = threadIdx.x;
    const int  lane = tid & (WSZ-1);
    const int  wid  = tid >> 6;
    const long long sw = (long long)blockIdx.x * NT + (long long)wid * WSZ;
    const long long s  = sw + lane;

    float* myb = s_buf + wid * (WSZ*63);

    // ---- 1) stage OWN wave's pose chunk (coalesced float4, rolled) ----
    {
        const float4* src = reinterpret_cast<const float4*>(body_pose + sw*63);
        float4* dst = reinterpret_cast<float4*>(myb);
        #pragma unroll 1
        for (int i = lane; i < WSZ*63/4; i += WSZ) dst[i] = src[i];   // 16 iters
    }

    // ---- 2) per-lane small inputs (fill under staging) ----
    const float gox = global_orient[s*3 + 0];
    const float goy = global_orient[s*3 + 1];
    const float goz = global_orient[s*3 + 2];
    const float trx = transl[s*3 + 0];
    const float try_ = transl[s*3 + 1];
    const float trz = transl[s*3 + 2];
    float bt[10];
    {
        const float2* b2 = reinterpret_cast<const float2*>(betas + s*10);
        #pragma unroll
        for (int k = 0; k < 5; ++k) {
            float2 v = b2[k];
            bt[2*k+0] = v.x; bt[2*k+1] = v.y;
        }
    }

    // ---- 3) tables (both waves write identical values; rolled loops) ----
    float* s_LD = reinterpret_cast<float*>(s_LD4);
    #pragma unroll 1
    for (int i = lane; i < NJ*3; i += WSZ) {
        int j = i/3, c = i - j*3;
        float v = J_template[i];
        if (j) v -= J_template[c_par[j]*3 + c];
        s_LD[i*12 + 10] = v;       // LT in pad slot
        s_LD[i*12 + 11] = 0.0f;
    }
    #pragma unroll 1
    for (int i = lane; i < NJ*30; i += WSZ) {
        int jc = i/10, k = i - jc*10;
        int j = jc/3,  c = jc - j*3;
        float v = J_shapedirs[i];
        if (j) v -= J_shapedirs[(c_par[j]*3 + c)*10 + k];
        s_LD[jc*12 + k] = v;
    }
    __builtin_amdgcn_wave_barrier();   // fence: staging/table writes before reads

    // ---- 4) root transform -> registers + s_root ----
    float g[12], g0r[12], g9r[12];
    rodrigues(gox, goy, goz, g0r);
    {
        float lt0[3];
        local_pos_rt(0, bt, s_LD4, lt0);
        g0r[9]  = lt0[0] + trx;
        g0r[10] = lt0[1] + try_;
        g0r[11] = lt0[2] + trz;
    }
    s_root[tid*3+0] = g0r[9]; s_root[tid*3+1] = g0r[10]; s_root[tid*3+2] = g0r[11];
    #pragma unroll
    for (int i = 0; i < 12; ++i) { g[i] = g0r[i]; g9r[i] = g0r[i]; }

    // ---- 5) FK: ONE rolled loop over 21 steps (small, I$-resident) ----
    float* pp = myb + lane*63;
    #pragma unroll 1
    for (int t = 0; t < 21; ++t) {
        const int code = c_code[t];       // uniform s_load
        const int j    = code & 255;
        const int src  = code >> 8;
        if (src == 1) {                   // uniform branch: restart from root
            #pragma unroll
            for (int i = 0; i < 12; ++i) g[i] = g0r[i];
        } else if (src == 2) {            // uniform branch: restart from g9
            #pragma unroll
            for (int i = 0; i < 12; ++i) g[i] = g9r[i];
        }
        const int pb = (j-1)*3;
        float R[9];
        rodrigues(pp[pb+0], pp[pb+1], pp[pb+2], R);
        float lt[3];
        local_pos_rt(j, bt, s_LD4, lt);
        float gn[12];
        #pragma unroll
        for (int r = 0; r < 3; ++r) {
            #pragma unroll
            for (int c = 0; c < 3; ++c)
                gn[r*3+c] = fmaf(g[r*3+0], R[c],
                            fmaf(g[r*3+1], R[3+c],
                                 g[r*3+2] * R[6+c]));
            gn[9+r] = fmaf(g[r*3+0], lt[0],
                      fmaf(g[r*3+1], lt[1],
                      fmaf(g[r*3+2], lt[2], g[9+r])));
        }
        #pragma unroll
        for (int i = 0; i < 12; ++i) g[i] = gn[i];
        pp[pb+0] = g[9]; pp[pb+1] = g[10]; pp[pb+2] = g[11];   // overlay consumed slot
        if (j == 9) {                     // uniform: capture g9
            #pragma unroll
            for (int i = 0; i < 12; ++i) g9r[i] = g[i];
        }
    }
    __builtin_amdgcn_wave_barrier();   // fence: FK writes before gather reads

    // ---- 6) coalesced float4 gather of OWN wave's outputs ----
    {
        const float* s_rootw = s_root + wid * (WSZ*3);
        float4* dst = reinterpret_cast<float4*>(out + sw * (NJ*3));
        #pragma unroll 1
        for (int i = lane; i < WSZ*66/4; i += WSZ) {     // 17 iters
            const int f0 = i*4;
            float v[4];
            #pragma unroll
            for (int q = 0; q < 4; ++q) {
                int f = f0 + q;
                int sm = f / 66;
                int r = f - sm*66;
                v[q] = (r < 3) ? s_rootw[sm*3 + r] : myb[sm*63 + (r - 3)];
            }
            dst[i] = make_float4(v[0], v[1], v[2], v[3]);
        }
    }
}

extern "C" void kernel_launch(void* const* d_in, const int* in_sizes, int n_in,
                              void* d_out, int out_size, void* d_ws, size_t ws_size,
                              hipStream_t stream) {
    const float* body_pose     = (const float*)d_in[0];
    const float* betas         = (const float*)d_in[1];
    const float* global_orient = (const float*)d_in[2];
    const float* transl        = (const float*)d_in[3];
    const float* J_template    = (const float*)d_in[4];
    const float* J_shapedirs   = (const float*)d_in[5];
    float* out = (float*)d_out;

    const int S = in_sizes[0] / 63;        // B*L = 131072 (divisible by NT)
    const int blocks = S / NT;

    hipLaunchKernelGGL(fk_joints_kernel, dim3(blocks), dim3(NT), 0, stream,
                       body_pose, betas, global_orient, transl,
                       J_template, J_shapedirs, out);
}

// Round 12
// 32.236 us; speedup vs baseline: 1.3868x; 1.0583x over previous
//
#include <hip/hip_runtime.h>

#define NT  128  // 2 waves/block; waves fully independent (zero __syncthreads)
#define WSZ 64
#define NJ  22

// FK schedule: code = j | (src<<8); src: 0=prev g, 1=g0, 2=g9.
// Parent skeleton position is CARRIED in registers along each chain.
__constant__ int c_code[21] = {
    1|(1<<8), 4, 7, 10,            // chain A (from g0)
    2|(1<<8), 5, 8, 11,            // chain B (from g0)
    3|(1<<8), 6, 9,                // chain C (from g0); g9/sk9 captured at j==9
    12|(2<<8), 15,                 // chain D (from g9)
    13|(2<<8), 16, 18, 20,         // chain E (from g9)
    14|(2<<8), 17, 19, 21          // chain F (from g9)
};

__device__ __forceinline__ void rodrigues(float ax, float ay, float az, float* R) {
    float sq   = ax*ax + ay*ay + az*az + 1e-12f;
    float rinv = rsqrtf(sq);
    float ang  = sq * rinv;          // sqrt(sq)
    float s, c;
    __sincosf(ang, &s, &c);
    float x = ax*rinv, y = ay*rinv, z = az*rinv;
    float t = 1.0f - c;
    R[0] = t*x*x + c;   R[1] = t*x*y - s*z; R[2] = t*x*z + s*y;
    R[3] = t*x*y + s*z; R[4] = t*y*y + c;   R[5] = t*y*z - s*x;
    R[6] = t*x*z - s*y; R[7] = t*y*z + s*x; R[8] = t*z*z + c;
}

__global__ __launch_bounds__(NT) void fk_joints_kernel(
    const float* __restrict__ body_pose,     // (S,63)
    const float* __restrict__ betas,         // (S,10)
    const float* __restrict__ global_orient, // (S,3)
    const float* __restrict__ transl,        // (S,3)
    const float* __restrict__ J_template,    // (22,3)   uniform idx -> s_load/K$
    const float* __restrict__ J_shapedirs,   // (22,3,10) uniform idx -> s_load/K$
    float* __restrict__ out)                 // (S,22,3)
{
    // Wave-private pose regions (64 x 63 floats); FK output for joint j overlays
    // the consumed pose slot (j-1). Root -> s_root. NO LDS tables (K$/SGPR path).
    __shared__ float s_buf[NT*63];           // 32256 B
    __shared__ float s_root[NT*3];           // 1536 B  (33.8 KB -> 4 blk/CU)

    const int  tid  = threadIdx.x;
    const int  lane = tid & (WSZ-1);
    const int  wid  = tid >> 6;
    const long long sw = (long long)blockIdx.x * NT + (long long)wid * WSZ;
    const long long s  = sw + lane;

    float* myb = s_buf + wid * (WSZ*63);

    // ---- 1) stage OWN wave's pose chunk (coalesced float4, rolled) ----
    {
        const float4* src = reinterpret_cast<const float4*>(body_pose + sw*63);
        float4* dst = reinterpret_cast<float4*>(myb);
        #pragma unroll 1
        for (int i = lane; i < WSZ*63/4; i += WSZ) dst[i] = src[i];   // 16 iters
    }

    // ---- 2) per-lane small inputs (fill under staging) ----
    const float gox = global_orient[s*3 + 0];
    const float goy = global_orient[s*3 + 1];
    const float goz = global_orient[s*3 + 2];
    const float trx = transl[s*3 + 0];
    const float try_ = transl[s*3 + 1];
    const float trz = transl[s*3 + 2];
    float bt[10];
    {
        const float2* b2 = reinterpret_cast<const float2*>(betas + s*10);
        #pragma unroll
        for (int k = 0; k < 5; ++k) {
            float2 v = b2[k];
            bt[2*k+0] = v.x; bt[2*k+1] = v.y;
        }
    }

    // ---- 3) root skeleton (scalar table rows) + root transform ----
    float sk0[3], sk9[3], skp[3];
    #pragma unroll
    for (int c = 0; c < 3; ++c) {
        float v = J_template[c];                       // uniform -> s_load
        #pragma unroll
        for (int k = 0; k < 10; ++k)
            v = fmaf(bt[k], J_shapedirs[c*10 + k], v); // v_fmac v,s,v
        sk0[c] = v;
    }
    float g[12], g0r[12], g9r[12];
    rodrigues(gox, goy, goz, g0r);
    g0r[9]  = sk0[0] + trx;
    g0r[10] = sk0[1] + try_;
    g0r[11] = sk0[2] + trz;
    s_root[tid*3+0] = g0r[9]; s_root[tid*3+1] = g0r[10]; s_root[tid*3+2] = g0r[11];
    #pragma unroll
    for (int i = 0; i < 12; ++i) { g[i] = g0r[i]; g9r[i] = g0r[i]; }
    #pragma unroll
    for (int c = 0; c < 3; ++c) { sk9[c] = sk0[c]; skp[c] = sk0[c]; }

    __builtin_amdgcn_wave_barrier();   // fence: staging writes before FK pose reads

    // ---- 4) FK: ONE rolled loop; table via K$/SGPR, pose via LDS, minimal DS ----
    float* pp = myb + lane*63;
    #pragma unroll 1
    for (int t = 0; t < 21; ++t) {
        const int code = c_code[t];       // uniform s_load
        const int j    = code & 255;
        const int src  = code >> 8;
        if (src == 1) {                   // uniform branch: restart from root
            #pragma unroll
            for (int i = 0; i < 12; ++i) g[i] = g0r[i];
            #pragma unroll
            for (int c = 0; c < 3; ++c) skp[c] = sk0[c];
        } else if (src == 2) {            // uniform branch: restart from g9
            #pragma unroll
            for (int i = 0; i < 12; ++i) g[i] = g9r[i];
            #pragma unroll
            for (int c = 0; c < 3; ++c) skp[c] = sk9[c];
        }

        // skeleton S_j from scalar-loaded table row (33 dwords, K$-hot)
        float sj[3];
        #pragma unroll
        for (int c = 0; c < 3; ++c) {
            float v = J_template[j*3 + c];
            #pragma unroll
            for (int k = 0; k < 10; ++k)
                v = fmaf(bt[k], J_shapedirs[(j*3 + c)*10 + k], v);
            sj[c] = v;
        }
        const float l0 = sj[0] - skp[0];
        const float l1 = sj[1] - skp[1];
        const float l2 = sj[2] - skp[2];

        const int pb = (j-1)*3;
        float R[9];
        rodrigues(pp[pb+0], pp[pb+1], pp[pb+2], R);

        float gn[12];
        #pragma unroll
        for (int r = 0; r < 3; ++r) {
            #pragma unroll
            for (int c = 0; c < 3; ++c)
                gn[r*3+c] = fmaf(g[r*3+0], R[c],
                            fmaf(g[r*3+1], R[3+c],
                                 g[r*3+2] * R[6+c]));
            gn[9+r] = fmaf(g[r*3+0], l0,
                      fmaf(g[r*3+1], l1,
                      fmaf(g[r*3+2], l2, g[9+r])));
        }
        #pragma unroll
        for (int i = 0; i < 12; ++i) g[i] = gn[i];
        pp[pb+0] = g[9]; pp[pb+1] = g[10]; pp[pb+2] = g[11];   // overlay consumed slot
        #pragma unroll
        for (int c = 0; c < 3; ++c) skp[c] = sj[c];            // carry parent skeleton
        if (j == 9) {                     // uniform: capture g9 state
            #pragma unroll
            for (int i = 0; i < 12; ++i) g9r[i] = g[i];
            #pragma unroll
            for (int c = 0; c < 3; ++c) sk9[c] = sj[c];
        }
    }
    __builtin_amdgcn_wave_barrier();   // fence: FK writes before gather reads

    // ---- 5) coalesced float4 gather of OWN wave's outputs ----
    {
        const float* s_rootw = s_root + wid * (WSZ*3);
        float4* dst = reinterpret_cast<float4*>(out + sw * (NJ*3));
        #pragma unroll 1
        for (int i = lane; i < WSZ*66/4; i += WSZ) {     // 17 iters
            const int f0 = i*4;
            float v[4];
            #pragma unroll
            for (int q = 0; q < 4; ++q) {
                int f = f0 + q;
                int sm = f / 66;
                int r = f - sm*66;
                v[q] = (r < 3) ? s_rootw[sm*3 + r] : myb[sm*63 + (r - 3)];
            }
            dst[i] = make_float4(v[0], v[1], v[2], v[3]);
        }
    }
}

extern "C" void kernel_launch(void* const* d_in, const int* in_sizes, int n_in,
                              void* d_out, int out_size, void* d_ws, size_t ws_size,
                              hipStream_t stream) {
    const float* body_pose     = (const float*)d_in[0];
    const float* betas         = (const float*)d_in[1];
    const float* global_orient = (const float*)d_in[2];
    const float* transl        = (const float*)d_in[3];
    const float* J_template    = (const float*)d_in[4];
    const float* J_shapedirs   = (const float*)d_in[5];
    float* out = (float*)d_out;

    const int S = in_sizes[0] / 63;        // B*L = 131072 (divisible by NT)
    const int blocks = S / NT;

    hipLaunchKernelGGL(fk_joints_kernel, dim3(blocks), dim3(NT), 0, stream,
                       body_pose, betas, global_orient, transl,
                       J_template, J_shapedirs, out);
}